// Round 3
// baseline (183.220 us; speedup 1.0000x reference)
//
#include <hip/hip_runtime.h>
#include <math.h>

#define HW 4096
#define CIN 256
#define DD 256
#define M_TOTAL 48
#define NSP 4
#define SPPX (HW / NSP)   // 1024 pixels per spatial slice

// ---------------------------------------------------------------------------
// K1 (fused): blocks 0..47  -> per-m flow + bilinear tap-weight scatter into a
//                             private LDS map, direct write to Ag[m] + Sg[m].
//             blocks 48..79 -> 64x64 tile transposes of W_emb and W_dc.
// 1024 threads/block.
// ---------------------------------------------------------------------------
__global__ __launch_bounds__(1024) void k_pre(
    const float* __restrict__ p_motions,
    const float* __restrict__ W_emb,
    const float* __restrict__ W_dc,
    float* __restrict__ Ag,      // [48][4096]
    float* __restrict__ Sg,      // [48]
    float* __restrict__ WembT,   // [c][k] = W_emb[k][c]
    float* __restrict__ WdcT)    // [k][o] = W_dc[o][k]
{
    __shared__ float smem[64 * 65];   // k1: first 4096 = tap map; transpose: [64][65]
    const int tid = threadIdx.x;
    const int bid = blockIdx.x;

    if (bid < M_TOTAL) {
        // ---------------- flow + scatter ----------------
        __shared__ float Ssum;
        const int m = bid;
        const float* p0 = p_motions + (size_t)m * 2 * 65536;  // dy
        const float* p1 = p0 + 65536;                         // dx

        for (int i = tid; i < HW; i += 1024) smem[i] = 0.f;
        if (tid == 0) Ssum = 0.f;
        __syncthreads();

        for (int i = tid; i < HW; i += 1024) {
            const int y = i >> 6, x = i & 63;
            const int r1 = 4 * y + 1, r2 = 4 * y + 2;
            const int c1 = 4 * x + 1, c2 = 4 * x + 2;
            // 256->64 bilinear resize degenerates to a 4-px average here
            float a = p0[r1 * 256 + c1], b = p0[r1 * 256 + c2];
            float c = p0[r2 * 256 + c1], d = p0[r2 * 256 + c2];
            float fy = (a + b + c + d) * 0.0625f;   // avg * 0.25 scale
            a = p1[r1 * 256 + c1]; b = p1[r1 * 256 + c2];
            c = p1[r2 * 256 + c1]; d = p1[r2 * 256 + c2];
            float fx = (a + b + c + d) * 0.0625f;

            const float yy = (float)y + fy;
            const float xx = (float)x + fx;
            const float y0f = floorf(yy), x0f = floorf(xx);
            const float wy = yy - y0f, wx = xx - x0f;
            const int iy0 = (int)y0f, ix0 = (int)x0f;
            const int iy1 = iy0 + 1, ix1 = ix0 + 1;
            const float w00 = (1.f - wy) * (1.f - wx);
            const float w01 = (1.f - wy) * wx;
            const float w10 = wy * (1.f - wx);
            const float w11 = wy * wx;
            const bool y0ok = (iy0 >= 0) & (iy0 < 64);
            const bool y1ok = (iy1 >= 0) & (iy1 < 64);
            const bool x0ok = (ix0 >= 0) & (ix0 < 64);
            const bool x1ok = (ix1 >= 0) & (ix1 < 64);
            if (y0ok & x0ok) atomicAdd(&smem[iy0 * 64 + ix0], w00);
            if (y0ok & x1ok) atomicAdd(&smem[iy0 * 64 + ix1], w01);
            if (y1ok & x0ok) atomicAdd(&smem[iy1 * 64 + ix0], w10);
            if (y1ok & x1ok) atomicAdd(&smem[iy1 * 64 + ix1], w11);
        }
        __syncthreads();

        float part = 0.f;
        float* AgM = Ag + (size_t)m * HW;
        for (int i = tid; i < HW; i += 1024) {
            const float v = smem[i];
            AgM[i] = v;
            part += v;
        }
        for (int off = 32; off > 0; off >>= 1) part += __shfl_down(part, off, 64);
        if ((tid & 63) == 0) atomicAdd(&Ssum, part);
        __syncthreads();
        if (tid == 0) Sg[m] = Ssum;
    } else {
        // ---------------- weight transposes ----------------
        const int t = bid - M_TOTAL;          // 0..31
        const float* src = (t < 16) ? W_emb : W_dc;
        float* dst       = (t < 16) ? WembT : WdcT;
        const int tt = t & 15;
        const int bi = tt >> 2, bj = tt & 3;  // 4x4 tiles of 64x64
        const int w = tid >> 6, lane = tid & 63;
        float (*Ld)[65] = (float (*)[65])smem;

        for (int r = w; r < 64; r += 16)
            Ld[r][lane] = src[(size_t)(bi * 64 + r) * 256 + bj * 64 + lane];
        __syncthreads();
        for (int r = w; r < 64; r += 16)
            dst[(size_t)(bj * 64 + r) * 256 + bi * 64 + lane] = Ld[lane][r];
    }
}

// ---------------------------------------------------------------------------
// K2: gpart[sp][m][ci] = sum_{p in slice} A[m,p] * i_features[fm,ci,p]
// Grid (fm=16, chunk=16, sp=4). A slices held in registers (12 float4/lane,
// L2-resident re-reads); i_features streamed once, fully coalesced.
// ---------------------------------------------------------------------------
__global__ __launch_bounds__(256, 4) void k_gather_dot(
    const float* __restrict__ i_features,
    const float* __restrict__ Ag,
    float* __restrict__ gpart)   // [NSP][48][256]
{
    const int fm = blockIdx.x;     // 0..15
    const int chunk = blockIdx.y;  // 0..15
    const int sp = blockIdx.z;     // 0..3
    const int tid = threadIdx.x;
    const int wave = tid >> 6, lane = tid & 63;
    const int m0 = fm * 3;

    const float4* A0 = (const float4*)(Ag + (size_t)(m0 + 0) * HW + sp * SPPX);
    const float4* A1 = (const float4*)(Ag + (size_t)(m0 + 1) * HW + sp * SPPX);
    const float4* A2 = (const float4*)(Ag + (size_t)(m0 + 2) * HW + sp * SPPX);
    float4 a0[4], a1[4], a2[4];
    #pragma unroll
    for (int k = 0; k < 4; ++k) {
        a0[k] = A0[lane + 64 * k];
        a1[k] = A1[lane + 64 * k];
        a2[k] = A2[lane + 64 * k];
    }

    #pragma unroll
    for (int c = 0; c < 4; ++c) {
        const int ci = chunk * 16 + wave * 4 + c;
        const float4* f4 = (const float4*)(i_features + ((size_t)fm * CIN + ci) * HW + sp * SPPX);
        float s0 = 0.f, s1 = 0.f, s2 = 0.f;
        #pragma unroll
        for (int k = 0; k < 4; ++k) {
            const float4 v = f4[lane + 64 * k];
            s0 += v.x * a0[k].x + v.y * a0[k].y + v.z * a0[k].z + v.w * a0[k].w;
            s1 += v.x * a1[k].x + v.y * a1[k].y + v.z * a1[k].z + v.w * a1[k].w;
            s2 += v.x * a2[k].x + v.y * a2[k].y + v.z * a2[k].z + v.w * a2[k].w;
        }
        #pragma unroll
        for (int off = 32; off > 0; off >>= 1) {
            s0 += __shfl_down(s0, off, 64);
            s1 += __shfl_down(s1, off, 64);
            s2 += __shfl_down(s2, off, 64);
        }
        if (lane == 0) {
            gpart[((size_t)sp * M_TOTAL + m0 + 0) * CIN + ci] = s0;
            gpart[((size_t)sp * M_TOTAL + m0 + 1) * CIN + ci] = s1;
            gpart[((size_t)sp * M_TOTAL + m0 + 2) * CIN + ci] = s2;
        }
    }
}

// ---------------------------------------------------------------------------
// K3: two chained coalesced GEMVs per m through transposed weights.
// out[m,o] = sum_k WdcT[k,o] * ( sum_c WembT[c,k]*g[m,c] + b_emb[k]*Sm )
//          + b_dc[o]
// ---------------------------------------------------------------------------
__global__ __launch_bounds__(256) void k_out(
    const float* __restrict__ gpart,
    const float* __restrict__ Sg,
    const float* __restrict__ WembT,
    const float* __restrict__ WdcT,
    const float* __restrict__ b_emb,
    const float* __restrict__ b_dc,
    float* __restrict__ out)
{
    __shared__ float gl[CIN];
    __shared__ float sm[DD];
    const int m = blockIdx.x;
    const int tid = threadIdx.x;

    float gv = 0.f;
    for (int sp = 0; sp < NSP; ++sp)
        gv += gpart[((size_t)sp * M_TOTAL + m) * CIN + tid];
    gl[tid] = gv * (1.f / 4096.f);
    __syncthreads();

    const float Sm = Sg[m] * (1.f / 4096.f);
    float acc = 0.f;
    #pragma unroll 8
    for (int c = 0; c < CIN; ++c)
        acc += gl[c] * WembT[(size_t)c * DD + tid];   // coalesced across lanes
    sm[tid] = acc + b_emb[tid] * Sm;
    __syncthreads();

    float acc2 = 0.f;
    #pragma unroll 8
    for (int k = 0; k < DD; ++k)
        acc2 += sm[k] * WdcT[(size_t)k * DD + tid];   // coalesced across lanes
    out[(size_t)m * DD + tid] = acc2 + b_dc[tid];
}

// ---------------------------------------------------------------------------
extern "C" void kernel_launch(void* const* d_in, const int* in_sizes, int n_in,
                              void* d_out, int out_size, void* d_ws, size_t ws_size,
                              hipStream_t stream) {
    // setup_inputs order: imgs, i_features, p_motions, W_emb, b_emb, W_dc, b_dc
    const float* i_features = (const float*)d_in[1];
    const float* p_motions  = (const float*)d_in[2];
    const float* W_emb      = (const float*)d_in[3];
    const float* b_emb      = (const float*)d_in[4];
    const float* W_dc       = (const float*)d_in[5];
    const float* b_dc       = (const float*)d_in[6];
    float* out = (float*)d_out;

    float* ws = (float*)d_ws;
    float* Ag    = ws;                                // 48*4096
    float* Sg    = Ag + (size_t)M_TOTAL * HW;         // 64 (48 used)
    float* WembT = Sg + 64;                           // 65536
    float* WdcT  = WembT + 65536;                     // 65536
    float* gpart = WdcT + 65536;                      // 4*48*256
    // total ~377k floats ~1.44 MB

    k_pre<<<M_TOTAL + 32, 1024, 0, stream>>>(p_motions, W_emb, W_dc,
                                             Ag, Sg, WembT, WdcT);
    dim3 g2(16, 16, NSP);
    k_gather_dot<<<g2, 256, 0, stream>>>(i_features, Ag, gpart);
    k_out<<<M_TOTAL, 256, 0, stream>>>(gpart, Sg, WembT, WdcT, b_emb, b_dc, out);
}

// Round 4
// 170.261 us; speedup vs baseline: 1.0761x; 1.0761x over previous
//
#include <hip/hip_runtime.h>
#include <math.h>

#define HW 4096
#define CIN 256
#define DD 256
#define M_TOTAL 48
#define NSP 4
#define SPPX (HW / NSP)   // 1024 pixels per spatial slice

// ---------------------------------------------------------------------------
// K1 (fused, 448 blocks x 256 thr):
//   blocks 0..191   : (m, sp) flow + bilinear tap-weight scatter. Coalesced
//                     float4 p_motion loads (taps are .y/.z of float4 idx x).
//                     Private LDS map -> skip-zero global atomicAdd into Ag.
//   blocks 192..447 : fold WT[ci][o] = sum_k W_dc[o,k]*W_emb[k,ci] (stored
//                     transposed for coalesced k_out reads) and
//                     bfold[o] = W_dc[o,:] . b_emb.
// Ag/Sg pre-zeroed via hipMemsetAsync.
// ---------------------------------------------------------------------------
__global__ __launch_bounds__(256) void k_pre(
    const float* __restrict__ p_motions,
    const float* __restrict__ W_emb,
    const float* __restrict__ b_emb,
    const float* __restrict__ W_dc,
    float* __restrict__ Ag,      // [48][4096]
    float* __restrict__ Sg,      // [48]
    float* __restrict__ WT,      // [256][256] = WT[ci*256+o]
    float* __restrict__ bfold)   // [256]
{
    const int tid = threadIdx.x;
    const int bid = blockIdx.x;

    if (bid < M_TOTAL * NSP) {
        // ---------------- flow + scatter ----------------
        __shared__ float Al[HW];     // 16 KB private partial map
        __shared__ float red[4];
        const int m = bid >> 2;
        const int sp = bid & 3;
        const float4* p0 = (const float4*)(p_motions + (size_t)m * 2 * 65536); // dy
        const float4* p1 = p0 + 65536 / 4;                                     // dx

        for (int i = tid; i < HW; i += 256) Al[i] = 0.f;
        __syncthreads();

        #pragma unroll
        for (int ii = 0; ii < SPPX / 256; ++ii) {
            const int i = ii * 256 + tid;          // 0..1023 within slab
            const int y = sp * 16 + (i >> 6);
            const int x = i & 63;
            const int r1 = 4 * y + 1, r2 = 4 * y + 2;
            // taps at cols 4x+1,4x+2 = elements .y/.z of float4 index x
            const float4 v10 = p0[r1 * 64 + x];
            const float4 v20 = p0[r2 * 64 + x];
            const float4 v11 = p1[r1 * 64 + x];
            const float4 v21 = p1[r2 * 64 + x];
            const float fy = (v10.y + v10.z + v20.y + v20.z) * 0.0625f; // avg*0.25
            const float fx = (v11.y + v11.z + v21.y + v21.z) * 0.0625f;

            const float yy = (float)y + fy;
            const float xx = (float)x + fx;
            const float y0f = floorf(yy), x0f = floorf(xx);
            const float wy = yy - y0f, wx = xx - x0f;
            const int iy0 = (int)y0f, ix0 = (int)x0f;
            const int iy1 = iy0 + 1, ix1 = ix0 + 1;
            const float w00 = (1.f - wy) * (1.f - wx);
            const float w01 = (1.f - wy) * wx;
            const float w10 = wy * (1.f - wx);
            const float w11 = wy * wx;
            const bool y0ok = (iy0 >= 0) & (iy0 < 64);
            const bool y1ok = (iy1 >= 0) & (iy1 < 64);
            const bool x0ok = (ix0 >= 0) & (ix0 < 64);
            const bool x1ok = (ix1 >= 0) & (ix1 < 64);
            if (y0ok & x0ok) atomicAdd(&Al[iy0 * 64 + ix0], w00);
            if (y0ok & x1ok) atomicAdd(&Al[iy0 * 64 + ix1], w01);
            if (y1ok & x0ok) atomicAdd(&Al[iy1 * 64 + ix0], w10);
            if (y1ok & x1ok) atomicAdd(&Al[iy1 * 64 + ix1], w11);
        }
        __syncthreads();

        float part = 0.f;
        float* AgM = Ag + (size_t)m * HW;
        for (int i = tid; i < HW; i += 256) {
            const float v = Al[i];
            part += v;
            if (v != 0.f) atomicAdd(&AgM[i], v);  // skip-zero scatter
        }
        for (int off = 32; off > 0; off >>= 1) part += __shfl_down(part, off, 64);
        if ((tid & 63) == 0) red[tid >> 6] = part;
        __syncthreads();
        if (tid == 0) atomicAdd(&Sg[m], red[0] + red[1] + red[2] + red[3]);
    } else {
        // ---------------- weight fold ----------------
        __shared__ float wdc[256];
        __shared__ float red2[4];
        const int o = bid - M_TOTAL * NSP;     // 0..255
        wdc[tid] = W_dc[(size_t)o * 256 + tid];
        __syncthreads();
        float acc = 0.f;
        #pragma unroll 8
        for (int k = 0; k < 256; ++k)
            acc += wdc[k] * W_emb[(size_t)k * 256 + tid];   // coalesced rows
        WT[(size_t)tid * 256 + o] = acc;                    // transposed store

        float pb = wdc[tid] * b_emb[tid];
        for (int off = 32; off > 0; off >>= 1) pb += __shfl_down(pb, off, 64);
        if ((tid & 63) == 0) red2[tid >> 6] = pb;
        __syncthreads();
        if (tid == 0) bfold[o] = red2[0] + red2[1] + red2[2] + red2[3];
    }
}

// ---------------------------------------------------------------------------
// K2: gpart[sp][m][ci] = sum_{p in slice} A[m,p] * i_features[fm,ci,p]
// Grid (fm=16, chunk=16, sp=4). A slices held in registers; i_features
// streamed once, fully coalesced float4.
// ---------------------------------------------------------------------------
__global__ __launch_bounds__(256, 4) void k_gather_dot(
    const float* __restrict__ i_features,
    const float* __restrict__ Ag,
    float* __restrict__ gpart)   // [NSP][48][256]
{
    const int fm = blockIdx.x;     // 0..15
    const int chunk = blockIdx.y;  // 0..15
    const int sp = blockIdx.z;     // 0..3
    const int tid = threadIdx.x;
    const int wave = tid >> 6, lane = tid & 63;
    const int m0 = fm * 3;

    const float4* A0 = (const float4*)(Ag + (size_t)(m0 + 0) * HW + sp * SPPX);
    const float4* A1 = (const float4*)(Ag + (size_t)(m0 + 1) * HW + sp * SPPX);
    const float4* A2 = (const float4*)(Ag + (size_t)(m0 + 2) * HW + sp * SPPX);
    float4 a0[4], a1[4], a2[4];
    #pragma unroll
    for (int k = 0; k < 4; ++k) {
        a0[k] = A0[lane + 64 * k];
        a1[k] = A1[lane + 64 * k];
        a2[k] = A2[lane + 64 * k];
    }

    #pragma unroll
    for (int c = 0; c < 4; ++c) {
        const int ci = chunk * 16 + wave * 4 + c;
        const float4* f4 = (const float4*)(i_features + ((size_t)fm * CIN + ci) * HW + sp * SPPX);
        float s0 = 0.f, s1 = 0.f, s2 = 0.f;
        #pragma unroll
        for (int k = 0; k < 4; ++k) {
            const float4 v = f4[lane + 64 * k];
            s0 += v.x * a0[k].x + v.y * a0[k].y + v.z * a0[k].z + v.w * a0[k].w;
            s1 += v.x * a1[k].x + v.y * a1[k].y + v.z * a1[k].z + v.w * a1[k].w;
            s2 += v.x * a2[k].x + v.y * a2[k].y + v.z * a2[k].z + v.w * a2[k].w;
        }
        #pragma unroll
        for (int off = 32; off > 0; off >>= 1) {
            s0 += __shfl_down(s0, off, 64);
            s1 += __shfl_down(s1, off, 64);
            s2 += __shfl_down(s2, off, 64);
        }
        if (lane == 0) {
            gpart[((size_t)sp * M_TOTAL + m0 + 0) * CIN + ci] = s0;
            gpart[((size_t)sp * M_TOTAL + m0 + 1) * CIN + ci] = s1;
            gpart[((size_t)sp * M_TOTAL + m0 + 2) * CIN + ci] = s2;
        }
    }
}

// ---------------------------------------------------------------------------
// K3: out[m,o] = sum_ci WT[ci,o]*g[m,ci] + bfold[o]*S[m]/4096 + b_dc[o]
// Single folded GEMV; WT reads lane-coalesced.
// ---------------------------------------------------------------------------
__global__ __launch_bounds__(256) void k_out(
    const float* __restrict__ gpart,
    const float* __restrict__ Sg,
    const float* __restrict__ WT,
    const float* __restrict__ bfold,
    const float* __restrict__ b_dc,
    float* __restrict__ out)
{
    __shared__ float gl[CIN];
    const int m = blockIdx.x;
    const int tid = threadIdx.x;

    float gv = 0.f;
    for (int sp = 0; sp < NSP; ++sp)
        gv += gpart[((size_t)sp * M_TOTAL + m) * CIN + tid];
    gl[tid] = gv * (1.f / 4096.f);
    __syncthreads();

    const float Sm = Sg[m] * (1.f / 4096.f);
    float acc = 0.f;
    #pragma unroll 8
    for (int ci = 0; ci < CIN; ++ci)
        acc += gl[ci] * WT[(size_t)ci * DD + tid];   // coalesced across lanes
    out[(size_t)m * DD + tid] = acc + bfold[tid] * Sm + b_dc[tid];
}

// ---------------------------------------------------------------------------
extern "C" void kernel_launch(void* const* d_in, const int* in_sizes, int n_in,
                              void* d_out, int out_size, void* d_ws, size_t ws_size,
                              hipStream_t stream) {
    // setup_inputs order: imgs, i_features, p_motions, W_emb, b_emb, W_dc, b_dc
    const float* i_features = (const float*)d_in[1];
    const float* p_motions  = (const float*)d_in[2];
    const float* W_emb      = (const float*)d_in[3];
    const float* b_emb      = (const float*)d_in[4];
    const float* W_dc       = (const float*)d_in[5];
    const float* b_dc       = (const float*)d_in[6];
    float* out = (float*)d_out;

    float* ws = (float*)d_ws;
    float* Ag    = ws;                                // 48*4096
    float* Sg    = Ag + (size_t)M_TOTAL * HW;         // 64 (48 used)
    float* WT    = Sg + 64;                           // 65536
    float* bfold = WT + 65536;                        // 256
    float* gpart = bfold + 256;                       // 4*48*256

    hipMemsetAsync(Ag, 0, ((size_t)M_TOTAL * HW + 64) * sizeof(float), stream);

    k_pre<<<M_TOTAL * NSP + DD, 256, 0, stream>>>(p_motions, W_emb, b_emb, W_dc,
                                                  Ag, Sg, WT, bfold);
    dim3 g2(16, 16, NSP);
    k_gather_dot<<<g2, 256, 0, stream>>>(i_features, Ag, gpart);
    k_out<<<M_TOTAL, 256, 0, stream>>>(gpart, Sg, WT, bfold, b_dc, out);
}

// Round 5
// 157.338 us; speedup vs baseline: 1.1645x; 1.0821x over previous
//
#include <hip/hip_runtime.h>
#include <math.h>

#define HW 4096
#define CIN 256
#define DD 256
#define M_TOTAL 48
#define NSP 4
#define SPPX (HW / NSP)   // 1024 pixels per spatial slice

// ---------------------------------------------------------------------------
// K1 (448 blocks x 256 thr):
//   blocks 0..191   : (m, sp) flow + bilinear tap scatter into a private LDS
//                     map, written WHOLE to Ag4[m][sp] (no memset, no global
//                     atomics). Partial sum -> Sg4[m][sp].
//   blocks 192..447 : fold WT[ci][o] = sum_k W_dc[o,k]*W_emb[k,ci] (stored
//                     transposed), bfold[o] = W_dc[o,:].b_emb, and zero a
//                     48-float slice of out.
// ---------------------------------------------------------------------------
__global__ __launch_bounds__(256) void k_pre(
    const float* __restrict__ p_motions,
    const float* __restrict__ W_emb,
    const float* __restrict__ b_emb,
    const float* __restrict__ W_dc,
    float* __restrict__ Ag4,     // [48][4][4096] partial maps
    float* __restrict__ Sg4,     // [48][4]
    float* __restrict__ WT,      // [256][256] = WT[ci*256+o]
    float* __restrict__ bfold,   // [256]
    float* __restrict__ out)     // zeroed here
{
    const int tid = threadIdx.x;
    const int bid = blockIdx.x;

    if (bid < M_TOTAL * NSP) {
        // ---------------- flow + scatter ----------------
        __shared__ float Al[HW];     // 16 KB private partial map
        __shared__ float red[4];
        const int m = bid >> 2;
        const int sp = bid & 3;
        const float4* p0 = (const float4*)(p_motions + (size_t)m * 2 * 65536); // dy
        const float4* p1 = p0 + 65536 / 4;                                     // dx

        for (int i = tid; i < HW; i += 256) Al[i] = 0.f;
        __syncthreads();

        #pragma unroll
        for (int ii = 0; ii < SPPX / 256; ++ii) {
            const int i = ii * 256 + tid;          // 0..1023 within slab
            const int y = sp * 16 + (i >> 6);
            const int x = i & 63;
            const int r1 = 4 * y + 1, r2 = 4 * y + 2;
            // taps at cols 4x+1,4x+2 = elements .y/.z of float4 index x
            const float4 v10 = p0[r1 * 64 + x];
            const float4 v20 = p0[r2 * 64 + x];
            const float4 v11 = p1[r1 * 64 + x];
            const float4 v21 = p1[r2 * 64 + x];
            const float fy = (v10.y + v10.z + v20.y + v20.z) * 0.0625f; // avg*0.25
            const float fx = (v11.y + v11.z + v21.y + v21.z) * 0.0625f;

            const float yy = (float)y + fy;
            const float xx = (float)x + fx;
            const float y0f = floorf(yy), x0f = floorf(xx);
            const float wy = yy - y0f, wx = xx - x0f;
            const int iy0 = (int)y0f, ix0 = (int)x0f;
            const int iy1 = iy0 + 1, ix1 = ix0 + 1;
            const float w00 = (1.f - wy) * (1.f - wx);
            const float w01 = (1.f - wy) * wx;
            const float w10 = wy * (1.f - wx);
            const float w11 = wy * wx;
            const bool y0ok = (iy0 >= 0) & (iy0 < 64);
            const bool y1ok = (iy1 >= 0) & (iy1 < 64);
            const bool x0ok = (ix0 >= 0) & (ix0 < 64);
            const bool x1ok = (ix1 >= 0) & (ix1 < 64);
            if (y0ok & x0ok) atomicAdd(&Al[iy0 * 64 + ix0], w00);
            if (y0ok & x1ok) atomicAdd(&Al[iy0 * 64 + ix1], w01);
            if (y1ok & x0ok) atomicAdd(&Al[iy1 * 64 + ix0], w10);
            if (y1ok & x1ok) atomicAdd(&Al[iy1 * 64 + ix1], w11);
        }
        __syncthreads();

        // write whole partial map (plain float4 stores) + partial sum
        const float4* Al4 = (const float4*)Al;
        float4* dst = (float4*)(Ag4 + (size_t)(m * NSP + sp) * HW);
        float part = 0.f;
        #pragma unroll
        for (int i = tid; i < HW / 4; i += 256) {
            const float4 v = Al4[i];
            dst[i] = v;
            part += v.x + v.y + v.z + v.w;
        }
        for (int off = 32; off > 0; off >>= 1) part += __shfl_down(part, off, 64);
        if ((tid & 63) == 0) red[tid >> 6] = part;
        __syncthreads();
        if (tid == 0) Sg4[m * NSP + sp] = red[0] + red[1] + red[2] + red[3];
    } else {
        // ---------------- weight fold + out zeroing ----------------
        __shared__ float wdc[256];
        __shared__ float red2[4];
        const int o = bid - M_TOTAL * NSP;     // 0..255
        wdc[tid] = W_dc[(size_t)o * 256 + tid];
        if (tid < 48) out[(size_t)o * 48 + tid] = 0.f;  // 256*48 = 48*256 floats
        __syncthreads();
        float acc = 0.f;
        #pragma unroll 8
        for (int k = 0; k < 256; ++k)
            acc += wdc[k] * W_emb[(size_t)k * 256 + tid];   // coalesced rows
        WT[(size_t)tid * 256 + o] = acc;                    // transposed store

        float pb = wdc[tid] * b_emb[tid];
        for (int off = 32; off > 0; off >>= 1) pb += __shfl_down(pb, off, 64);
        if ((tid & 63) == 0) red2[tid >> 6] = pb;
        __syncthreads();
        if (tid == 0) bfold[o] = red2[0] + red2[1] + red2[2] + red2[3];
    }
}

// ---------------------------------------------------------------------------
// K2: gather + epilogue fused. Grid (fm=16, chunk=16, sp=4).
// Each block: sum 4 partial A slices into registers, dot with 16 channels of
// i_features (streamed once, coalesced), wave-reduce, then apply the 16x256
// WT slice and atomicAdd into out. Bias added by (chunk==0, sp==0) blocks.
// ---------------------------------------------------------------------------
__global__ __launch_bounds__(256, 4) void k_gather_out(
    const float* __restrict__ i_features,
    const float* __restrict__ Ag4,
    const float* __restrict__ Sg4,
    const float* __restrict__ WT,
    const float* __restrict__ bfold,
    const float* __restrict__ b_dc,
    float* __restrict__ out)
{
    __shared__ float gl[3][16];
    const int fm = blockIdx.x;     // 0..15
    const int chunk = blockIdx.y;  // 0..15
    const int sp = blockIdx.z;     // 0..3
    const int tid = threadIdx.x;
    const int wave = tid >> 6, lane = tid & 63;
    const int m0 = fm * 3;

    // sum the 4 partial A maps for this slice into registers
    float4 a[3][4];
    #pragma unroll
    for (int j = 0; j < 3; ++j) {
        const float4* P0 = (const float4*)(Ag4 + ((size_t)((m0 + j) * NSP + 0)) * HW + sp * SPPX);
        const float4* P1 = (const float4*)(Ag4 + ((size_t)((m0 + j) * NSP + 1)) * HW + sp * SPPX);
        const float4* P2 = (const float4*)(Ag4 + ((size_t)((m0 + j) * NSP + 2)) * HW + sp * SPPX);
        const float4* P3 = (const float4*)(Ag4 + ((size_t)((m0 + j) * NSP + 3)) * HW + sp * SPPX);
        #pragma unroll
        for (int k = 0; k < 4; ++k) {
            const float4 t0 = P0[lane + 64 * k];
            const float4 t1 = P1[lane + 64 * k];
            const float4 t2 = P2[lane + 64 * k];
            const float4 t3 = P3[lane + 64 * k];
            a[j][k].x = t0.x + t1.x + t2.x + t3.x;
            a[j][k].y = t0.y + t1.y + t2.y + t3.y;
            a[j][k].z = t0.z + t1.z + t2.z + t3.z;
            a[j][k].w = t0.w + t1.w + t2.w + t3.w;
        }
    }

    #pragma unroll
    for (int c = 0; c < 4; ++c) {
        const int ci = chunk * 16 + wave * 4 + c;
        const float4* f4 = (const float4*)(i_features + ((size_t)fm * CIN + ci) * HW + sp * SPPX);
        float s0 = 0.f, s1 = 0.f, s2 = 0.f;
        #pragma unroll
        for (int k = 0; k < 4; ++k) {
            const float4 v = f4[lane + 64 * k];
            s0 += v.x * a[0][k].x + v.y * a[0][k].y + v.z * a[0][k].z + v.w * a[0][k].w;
            s1 += v.x * a[1][k].x + v.y * a[1][k].y + v.z * a[1][k].z + v.w * a[1][k].w;
            s2 += v.x * a[2][k].x + v.y * a[2][k].y + v.z * a[2][k].z + v.w * a[2][k].w;
        }
        #pragma unroll
        for (int off = 32; off > 0; off >>= 1) {
            s0 += __shfl_down(s0, off, 64);
            s1 += __shfl_down(s1, off, 64);
            s2 += __shfl_down(s2, off, 64);
        }
        if (lane == 0) {
            gl[0][wave * 4 + c] = s0;
            gl[1][wave * 4 + c] = s1;
            gl[2][wave * 4 + c] = s2;
        }
    }
    __syncthreads();

    // epilogue: out[m, o] += sum_q gl[m][q] * WT[chunk*16+q, o] / 4096
    const int o = tid;
    float acc0 = 0.f, acc1 = 0.f, acc2 = 0.f;
    #pragma unroll
    for (int q = 0; q < 16; ++q) {
        const float wv = WT[(size_t)(chunk * 16 + q) * DD + o];  // coalesced
        acc0 += gl[0][q] * wv;
        acc1 += gl[1][q] * wv;
        acc2 += gl[2][q] * wv;
    }
    const float inv = 1.f / 4096.f;
    atomicAdd(&out[(size_t)(m0 + 0) * DD + o], acc0 * inv);
    atomicAdd(&out[(size_t)(m0 + 1) * DD + o], acc1 * inv);
    atomicAdd(&out[(size_t)(m0 + 2) * DD + o], acc2 * inv);

    // bias (once per m): blocks with chunk==0 && sp==0
    if (chunk == 0 && sp == 0) {
        #pragma unroll
        for (int j = 0; j < 3; ++j) {
            const int m = m0 + j;
            const float Sm = (Sg4[m * NSP + 0] + Sg4[m * NSP + 1] +
                              Sg4[m * NSP + 2] + Sg4[m * NSP + 3]) * inv;
            atomicAdd(&out[(size_t)m * DD + tid], bfold[tid] * Sm + b_dc[tid]);
        }
    }
}

// ---------------------------------------------------------------------------
extern "C" void kernel_launch(void* const* d_in, const int* in_sizes, int n_in,
                              void* d_out, int out_size, void* d_ws, size_t ws_size,
                              hipStream_t stream) {
    // setup_inputs order: imgs, i_features, p_motions, W_emb, b_emb, W_dc, b_dc
    const float* i_features = (const float*)d_in[1];
    const float* p_motions  = (const float*)d_in[2];
    const float* W_emb      = (const float*)d_in[3];
    const float* b_emb      = (const float*)d_in[4];
    const float* W_dc       = (const float*)d_in[5];
    const float* b_dc       = (const float*)d_in[6];
    float* out = (float*)d_out;

    float* ws = (float*)d_ws;
    float* Ag4   = ws;                                   // 48*4*4096 = 786432
    float* Sg4   = Ag4 + (size_t)M_TOTAL * NSP * HW;     // 192 (pad 256)
    float* WT    = Sg4 + 256;                            // 65536
    float* bfold = WT + 65536;                           // 256
    // total ~3.25 MB

    k_pre<<<M_TOTAL * NSP + DD, 256, 0, stream>>>(p_motions, W_emb, b_emb, W_dc,
                                                  Ag4, Sg4, WT, bfold, out);
    dim3 g2(16, 16, NSP);
    k_gather_out<<<g2, 256, 0, stream>>>(i_features, Ag4, Sg4, WT, bfold, b_dc, out);
}